// Round 1
// baseline (180.572 us; speedup 1.0000x reference)
//
#include <hip/hip_runtime.h>
#include <hip/hip_bf16.h>

// B=4, G=1024, D=512, H=8, dh=64. NUM_BUCKETS=32, MAX_DIST=128, base=2.
typedef __attribute__((ext_vector_type(8))) short bf16x8;
typedef __attribute__((ext_vector_type(4))) float f32x4;

__device__ __forceinline__ unsigned short f2bf(float x) {
  union { __hip_bfloat16 h; unsigned short u; } cv;
  cv.h = __float2bfloat16(x);
  return cv.u;
}

__device__ __forceinline__ void gload16(const void* g, void* l) {
  __builtin_amdgcn_global_load_lds(
      (const __attribute__((address_space(1))) unsigned int*)g,
      (__attribute__((address_space(3))) unsigned int*)l, 16, 0, 0);
}

// swizzled byte offset for 128B-row LDS tiles: spreads same-column reads over banks
__device__ __forceinline__ int swz128(int row, int colb) {
  return row * 128 + (colb ^ ((row & 7) << 4));
}

// ---------------- fp32 -> bf16 conversion (all tensors, one launch) -------------
__global__ __launch_bounds__(256)
void k_cvt_all(const float* __restrict__ q, const float* __restrict__ k,
               const float* __restrict__ v, const float* __restrict__ Wq,
               const float* __restrict__ Wk, const float* __restrict__ Wv,
               const float* __restrict__ Wo,
               unsigned short* __restrict__ XQ, unsigned short* __restrict__ XK,
               unsigned short* __restrict__ XV, unsigned short* __restrict__ WQB,
               unsigned short* __restrict__ WKB, unsigned short* __restrict__ WVB,
               unsigned short* __restrict__ WOB)
{
  long i = ((long)blockIdx.x * 256 + threadIdx.x) * 8;
  const float* s; unsigned short* d; long off;
  if (i < 2097152)      { s = q; d = XQ; off = i; }
  else if (i < 4194304) { s = k; d = XK; off = i - 2097152; }
  else if (i < 6291456) { s = v; d = XV; off = i - 4194304; }
  else {
    long j = i - 6291456;
    int wsel = (int)(j >> 18);
    off = j & 262143;
    s = wsel == 0 ? Wq : wsel == 1 ? Wk : wsel == 2 ? Wv : Wo;
    d = wsel == 0 ? WQB : wsel == 1 ? WKB : wsel == 2 ? WVB : WOB;
  }
  float4 a = *(const float4*)(s + off);
  float4 bb = *(const float4*)(s + off + 4);
  bf16x8 o;
  o[0] = (short)f2bf(a.x);  o[1] = (short)f2bf(a.y);
  o[2] = (short)f2bf(a.z);  o[3] = (short)f2bf(a.w);
  o[4] = (short)f2bf(bb.x); o[5] = (short)f2bf(bb.y);
  o[6] = (short)f2bf(bb.z); o[7] = (short)f2bf(bb.w);
  *(bf16x8*)(d + off) = o;
}

// ---------------- relative-position buckets: (B,G,G) u16 = bx | by<<8 -----------
__device__ __forceinline__ int rbucket(float dd) {
  float ad = fabsf(dd);
  float n = fminf(fmaxf(ad, 1e-6f), 128.0f);
  int li = (int)floorf(logf(n) * 1.4426950408889634f);
  li = li < 0 ? 0 : (li > 31 ? 31 : li);
  int s = (dd > 0.f) ? 1 : ((dd < 0.f) ? -1 : 0);
  return li * s + 31;
}

__global__ __launch_bounds__(256)
void k_buckets(const float* __restrict__ coords, unsigned short* __restrict__ buk) {
  int b = blockIdx.y;
  int f = blockIdx.x * 256 + threadIdx.x;   // q*1024 + k
  int qi = f >> 10, ki = f & 1023;
  const float* cb = coords + (b << 11);
  float qx = cb[qi * 2], qy = cb[qi * 2 + 1];
  float kx = cb[ki * 2], ky = cb[ki * 2 + 1];
  int bx = rbucket(qx - kx);
  int by = rbucket(qy - ky);
  buk[((long)b << 20) + f] = (unsigned short)(bx | (by << 8));
}

// ---------------- shared GEMM core: C = A(M,512) @ Bw(N,512)^T, bf16 MFMA -------
// 128x128 tile, 4 waves (2x2), BK=32, m97 structure.
__device__ __forceinline__ void gemm_core(
    const unsigned short* __restrict__ A, const unsigned short* __restrict__ Bw,
    int m0, int n0, unsigned short* ldsA, unsigned short* ldsB, f32x4 acc[4][4])
{
  const int t = threadIdx.x;
  const int lane = t & 63;
  const int w = t >> 6;
  const int wm = (w >> 1) << 6;
  const int wn = (w & 1) << 6;
  const int l15 = lane & 15;
  const int l4 = lane >> 4;
  const f32x4 fz = {0.f, 0.f, 0.f, 0.f};

  #pragma unroll
  for (int r = 0; r < 4; ++r)
    #pragma unroll
    for (int c = 0; c < 4; ++c) acc[r][c] = fz;

  for (int k0 = 0; k0 < 512; k0 += 32) {
    #pragma unroll
    for (int rr = 0; rr < 2; ++rr) {
      int c = rr * 256 + t;          // 16B chunk id; row=c>>2 (64B rows), col chunk=c&3
      int row = c >> 2, cc = c & 3;
      gload16(A + (m0 + row) * 512 + k0 + cc * 8, (char*)ldsA + c * 16);
      gload16(Bw + (n0 + row) * 512 + k0 + cc * 8, (char*)ldsB + c * 16);
    }
    __syncthreads();
    bf16x8 af[4], bfr[4];
    #pragma unroll
    for (int r = 0; r < 4; ++r) {
      af[r]  = *(const bf16x8*)((const char*)ldsA + (wm + r * 16 + l15) * 64 + l4 * 16);
      bfr[r] = *(const bf16x8*)((const char*)ldsB + (wn + r * 16 + l15) * 64 + l4 * 16);
    }
    #pragma unroll
    for (int r = 0; r < 4; ++r)
      #pragma unroll
      for (int c = 0; c < 4; ++c)
        acc[r][c] = __builtin_amdgcn_mfma_f32_16x16x32_bf16(af[r], bfr[c], acc[r][c], 0, 0, 0);
    __syncthreads();
  }
}

// ---------------- Q/K/V projections -> (B,H,G,64) bf16 (V to temp, transposed later)
__global__ __launch_bounds__(256)
void k_gemm_proj(const unsigned short* __restrict__ XQ, const unsigned short* __restrict__ XK,
                 const unsigned short* __restrict__ XV, const unsigned short* __restrict__ WQ,
                 const unsigned short* __restrict__ WK, const unsigned short* __restrict__ WV,
                 const float* __restrict__ bq, const float* __restrict__ bk,
                 const float* __restrict__ bv,
                 unsigned short* __restrict__ QP, unsigned short* __restrict__ KP,
                 unsigned short* __restrict__ VT)
{
  __shared__ unsigned short ldsA[128 * 32];
  __shared__ unsigned short ldsB[128 * 32];
  int z = blockIdx.z;
  const unsigned short* A = z == 0 ? XQ : z == 1 ? XK : XV;
  const unsigned short* W = z == 0 ? WQ : z == 1 ? WK : WV;
  const float* bias = z == 0 ? bq : z == 1 ? bk : bv;
  unsigned short* dst = z == 0 ? QP : z == 1 ? KP : VT;
  int m0 = blockIdx.x * 128, n0 = blockIdx.y * 128;
  f32x4 acc[4][4];
  gemm_core(A, W, m0, n0, ldsA, ldsB, acc);

  const int t = threadIdx.x, lane = t & 63, w = t >> 6;
  const int wm = (w >> 1) << 6, wn = (w & 1) << 6;
  const int l15 = lane & 15, l4 = lane >> 4;
  #pragma unroll
  for (int r = 0; r < 4; ++r)
    #pragma unroll
    for (int c = 0; c < 4; ++c)
      #pragma unroll
      for (int i = 0; i < 4; ++i) {
        int m = m0 + wm + r * 16 + (l4 << 2) + i;   // token
        int n = n0 + wn + c * 16 + l15;             // channel
        float y = acc[r][c][i] + bias[n];
        int b = m >> 10, g = m & 1023, hh = n >> 6, dd = n & 63;
        dst[((((b << 3) + hh) << 10) + g) * 64 + dd] = f2bf(y);
      }
}

// ---------------- V transpose: (BH,1024,64) -> (BH,64,1024) ---------------------
__global__ __launch_bounds__(256)
void k_transp(const unsigned short* __restrict__ src, unsigned short* __restrict__ dst) {
  __shared__ unsigned short tile[64][70];
  int bh = blockIdx.y;
  int g0 = blockIdx.x << 6;
  int t = threadIdx.x;
  int gr = t >> 6;
  int c = t & 63;
  #pragma unroll
  for (int rr = 0; rr < 16; ++rr) {
    int g = (rr << 2) + gr;
    tile[g][c] = src[(((long)bh << 10) + g0 + g) * 64 + c];
  }
  __syncthreads();
  #pragma unroll
  for (int rr = 0; rr < 16; ++rr) {
    int d = (rr << 2) + gr;
    dst[(((long)bh << 6) + d) * 1024 + g0 + c] = tile[c][d];
  }
}

// ---------------- flash attention ----------------------------------------------
// grid (16 q-blocks, 32 bh), 256 threads; wave w owns 16 q rows; KT=64.
__global__ __launch_bounds__(256)
void k_attn(const unsigned short* __restrict__ QP, const unsigned short* __restrict__ KP,
            const unsigned short* __restrict__ VPT, const unsigned short* __restrict__ BUK,
            const int* __restrict__ mask, const float* __restrict__ rpe_x,
            const float* __restrict__ rpe_y, unsigned short* __restrict__ AO)
{
  __shared__ unsigned short Qs[64 * 64];     // 64 q rows x 64 dh, swizzled
  __shared__ unsigned short Ks[64 * 64];     // 64 keys x 64 dh, swizzled
  __shared__ unsigned short Vs[64 * 64];     // 64 dh x 64 keys (V^T), swizzled
  __shared__ unsigned short Ps[4 * 16 * 64]; // per-wave P tile, swizzled
  __shared__ float rx[63], ry[63];

  const int t = threadIdx.x;
  const int lane = t & 63;
  const int w = t >> 6;
  const int l15 = lane & 15;
  const int l4 = lane >> 4;
  const int bh = blockIdx.y;
  const int b = bh >> 3, h = bh & 7;
  const int q0 = blockIdx.x << 6;
  const f32x4 fz = {0.f, 0.f, 0.f, 0.f};

  const unsigned short* Qg = QP + ((long)((bh << 10) + q0)) * 64;
  const unsigned short* Kg = KP + ((long)(bh << 10)) * 64;
  const unsigned short* Vg = VPT + ((long)(bh << 6)) * 1024;
  const int* maskb = mask + (b << 10);
  const unsigned short* bkb = BUK + ((long)b << 20);

  // stage Q (source pre-swizzled so linear global_load_lds dest == swizzled layout)
  #pragma unroll
  for (int rr = 0; rr < 2; ++rr) {
    int c = rr * 256 + t;
    int row = c >> 3, cc = c & 7;
    int gcc = cc ^ (row & 7);
    gload16(Qg + row * 64 + gcc * 8, (char*)Qs + c * 16);
  }
  if (t < 63) { rx[t] = rpe_x[t * 8 + h]; ry[t] = rpe_y[t * 8 + h]; }
  __syncthreads();

  bf16x8 qf[2];
  #pragma unroll
  for (int ks = 0; ks < 2; ++ks)
    qf[ks] = *(const bf16x8*)((const char*)Qs + swz128((w << 4) + l15, ks * 64 + l4 * 16));

  float mrun[4], lrun[4];
  f32x4 oacc[4];
  #pragma unroll
  for (int i = 0; i < 4; ++i) { mrun[i] = -1e30f; lrun[i] = 0.f; }
  #pragma unroll
  for (int dj = 0; dj < 4; ++dj) oacc[dj] = fz;

  for (int kt = 0; kt < 1024; kt += 64) {
    // stage K and V^T tiles
    #pragma unroll
    for (int rr = 0; rr < 2; ++rr) {
      int c = rr * 256 + t;
      int row = c >> 3, cc = c & 7;
      int gcc = cc ^ (row & 7);
      gload16(Kg + (kt + row) * 64 + gcc * 8, (char*)Ks + c * 16);
      gload16(Vg + row * 1024 + kt + gcc * 8, (char*)Vs + c * 16);
    }
    // mask + bucket loads (issued before barrier to hide latency)
    int mk[4];
    #pragma unroll
    for (int nj = 0; nj < 4; ++nj) mk[nj] = maskb[kt + nj * 16 + l15];
    unsigned short bko[4][4];
    #pragma unroll
    for (int i = 0; i < 4; ++i) {
      int qrow = q0 + (w << 4) + (l4 << 2) + i;
      #pragma unroll
      for (int nj = 0; nj < 4; ++nj)
        bko[i][nj] = bkb[((long)qrow << 10) + kt + nj * 16 + l15];
    }
    __syncthreads();

    // S = Q K^T  (raw, scale folded into softmax fma)
    f32x4 sacc[4];
    #pragma unroll
    for (int nj = 0; nj < 4; ++nj) sacc[nj] = fz;
    #pragma unroll
    for (int nj = 0; nj < 4; ++nj)
      #pragma unroll
      for (int ks = 0; ks < 2; ++ks) {
        bf16x8 kf = *(const bf16x8*)((const char*)Ks + swz128(nj * 16 + l15, ks * 64 + l4 * 16));
        sacc[nj] = __builtin_amdgcn_mfma_f32_16x16x32_bf16(qf[ks], kf, sacc[nj], 0, 0, 0);
      }

    // online softmax: rows are (l4*4+i); 16-lane groups hold one row
    float fsc[4];
    float pv_[4][4];
    #pragma unroll
    for (int i = 0; i < 4; ++i) {
      float sv[4];
      float vm = -1e30f;
      #pragma unroll
      for (int nj = 0; nj < 4; ++nj) {
        unsigned bkv = bko[i][nj];
        float bias = rx[bkv & 255] + ry[bkv >> 8];
        float s = fmaf(sacc[nj][i], 0.125f, bias);
        s = (mk[nj] == 0) ? -1e30f : s;
        sv[nj] = s;
        vm = fmaxf(vm, s);
      }
      vm = fmaxf(vm, __shfl_xor(vm, 1));
      vm = fmaxf(vm, __shfl_xor(vm, 2));
      vm = fmaxf(vm, __shfl_xor(vm, 4));
      vm = fmaxf(vm, __shfl_xor(vm, 8));
      float mo = mrun[i];
      float mn = fmaxf(mo, vm);
      float f = __expf(mo - mn);
      float ps = 0.f;
      #pragma unroll
      for (int nj = 0; nj < 4; ++nj) {
        float p = __expf(sv[nj] - mn);
        pv_[i][nj] = p;
        ps += p;
      }
      ps += __shfl_xor(ps, 1);
      ps += __shfl_xor(ps, 2);
      ps += __shfl_xor(ps, 4);
      ps += __shfl_xor(ps, 8);
      lrun[i] = lrun[i] * f + ps;
      mrun[i] = mn;
      fsc[i] = f;
    }
    #pragma unroll
    for (int dj = 0; dj < 4; ++dj)
      #pragma unroll
      for (int i = 0; i < 4; ++i) oacc[dj][i] *= fsc[i];

    // P -> LDS (bf16, swizzled); wave-private region, in-wave lgkm ordering suffices
    unsigned short* Pw = Ps + (w << 10);
    #pragma unroll
    for (int i = 0; i < 4; ++i) {
      int prow = (l4 << 2) + i;
      #pragma unroll
      for (int nj = 0; nj < 4; ++nj) {
        int pcolb = (nj * 16 + l15) * 2;
        *(unsigned short*)((char*)Pw + swz128(prow, pcolb)) = f2bf(pv_[i][nj]);
      }
    }

    // O += P V
    bf16x8 pf[2];
    #pragma unroll
    for (int ks = 0; ks < 2; ++ks)
      pf[ks] = *(const bf16x8*)((const char*)Pw + swz128(l15, ks * 64 + l4 * 16));
    #pragma unroll
    for (int dj = 0; dj < 4; ++dj)
      #pragma unroll
      for (int ks = 0; ks < 2; ++ks) {
        bf16x8 vf = *(const bf16x8*)((const char*)Vs + swz128(dj * 16 + l15, ks * 64 + l4 * 16));
        oacc[dj] = __builtin_amdgcn_mfma_f32_16x16x32_bf16(pf[ks], vf, oacc[dj], 0, 0, 0);
      }
    __syncthreads();
  }

  // normalize + store (B,G,512) bf16
  #pragma unroll
  for (int dj = 0; dj < 4; ++dj)
    #pragma unroll
    for (int i = 0; i < 4; ++i) {
      int g = q0 + (w << 4) + (l4 << 2) + i;
      int dd = dj * 16 + l15;
      float o = oacc[dj][i] / lrun[i];
      AO[((long)((b << 10) + g)) * 512 + h * 64 + dd] = f2bf(o);
    }
}

// ---------------- output projection: out = AO @ Wo^T + bo (fp32 out) ------------
__global__ __launch_bounds__(256)
void k_gemm_out(const unsigned short* __restrict__ AO, const unsigned short* __restrict__ WO,
                const float* __restrict__ bo, float* __restrict__ out)
{
  __shared__ unsigned short ldsA[128 * 32];
  __shared__ unsigned short ldsB[128 * 32];
  int m0 = blockIdx.x * 128, n0 = blockIdx.y * 128;
  f32x4 acc[4][4];
  gemm_core(AO, WO, m0, n0, ldsA, ldsB, acc);

  const int t = threadIdx.x, lane = t & 63, w = t >> 6;
  const int wm = (w >> 1) << 6, wn = (w & 1) << 6;
  const int l15 = lane & 15, l4 = lane >> 4;
  #pragma unroll
  for (int r = 0; r < 4; ++r)
    #pragma unroll
    for (int c = 0; c < 4; ++c)
      #pragma unroll
      for (int i = 0; i < 4; ++i) {
        int m = m0 + wm + r * 16 + (l4 << 2) + i;
        int n = n0 + wn + c * 16 + l15;
        out[(long)m * 512 + n] = acc[r][c][i] + bo[n];
      }
}

// ---------------- launch ---------------------------------------------------------
extern "C" void kernel_launch(void* const* d_in, const int* in_sizes, int n_in,
                              void* d_out, int out_size, void* d_ws, size_t ws_size,
                              hipStream_t stream) {
  const float* q      = (const float*)d_in[0];
  const float* k      = (const float*)d_in[1];
  const float* v      = (const float*)d_in[2];
  const float* coords = (const float*)d_in[3];
  const int*   mask   = (const int*)d_in[4];
  const float* Wq     = (const float*)d_in[5];
  const float* bq     = (const float*)d_in[6];
  const float* Wk     = (const float*)d_in[7];
  const float* bk     = (const float*)d_in[8];
  const float* Wv     = (const float*)d_in[9];
  const float* bv     = (const float*)d_in[10];
  const float* Wo     = (const float*)d_in[11];
  const float* bo     = (const float*)d_in[12];
  const float* rpe_x  = (const float*)d_in[13];
  const float* rpe_y  = (const float*)d_in[14];
  float* out = (float*)d_out;

  unsigned short* WQB  = (unsigned short*)d_ws;
  unsigned short* WKB  = WQB + 262144;
  unsigned short* WVB  = WKB + 262144;
  unsigned short* WOB  = WVB + 262144;
  unsigned short* XQ   = WOB + 262144;
  unsigned short* XK   = XQ + 2097152;
  unsigned short* XV   = XK + 2097152;
  unsigned short* QP   = XV + 2097152;
  unsigned short* KP   = QP + 2097152;
  unsigned short* VTMP = KP + 2097152;
  unsigned short* VPT  = VTMP + 2097152;
  unsigned short* AO   = VPT + 2097152;
  unsigned short* BUK  = AO + 2097152;   // 4,194,304 u16

  k_cvt_all<<<dim3(3584), dim3(256), 0, stream>>>(q, k, v, Wq, Wk, Wv, Wo,
                                                  XQ, XK, XV, WQB, WKB, WVB, WOB);
  k_buckets<<<dim3(4096, 4), dim3(256), 0, stream>>>(coords, BUK);
  k_gemm_proj<<<dim3(32, 4, 3), dim3(256), 0, stream>>>(XQ, XK, XV, WQB, WKB, WVB,
                                                        bq, bk, bv, QP, KP, VTMP);
  k_transp<<<dim3(16, 32), dim3(256), 0, stream>>>(VTMP, VPT);
  k_attn<<<dim3(16, 32), dim3(256), 0, stream>>>(QP, KP, VPT, BUK, mask,
                                                 rpe_x, rpe_y, AO);
  k_gemm_out<<<dim3(32, 4), dim3(256), 0, stream>>>(AO, WOB, bo, out);
}